// Round 9
// baseline (115.396 us; speedup 1.0000x reference)
//
#include <hip/hip_runtime.h>

typedef unsigned short ushort_t;
typedef unsigned int uint_t;
typedef __attribute__((ext_vector_type(8))) _Float16 half8;
typedef __attribute__((ext_vector_type(4))) float f32x4;

// Problem constants (B=1)
constexpr int DD = 8, HH = 24, WW = 24;
constexpr int NQ = DD * HH * WW;      // 4608
constexpr int CIN = 192;
constexpr int CQKV = 576;
constexpr int KW = 192;               // f16 W panel K-stride (single panel)
constexpr float SCALE_LOG2E = 0.17677669529663687f * 1.4426950408889634f;
constexpr int NROW = DD * HH;         // 192

// ---------------------------------------------------------------------------
// bf16 / f16 helpers
// ---------------------------------------------------------------------------
__device__ __forceinline__ ushort_t bf16h(float x) {
    uint_t u = __float_as_uint(x);
    u += 0x7FFFu + ((u >> 16) & 1u);
    return (ushort_t)(u >> 16);
}
// one packed-bf16 uint -> float2 {even, odd}
__device__ __forceinline__ float2 unpack2(uint_t u) {
    return make_float2(__uint_as_float(u << 16),
                       __uint_as_float(u & 0xffff0000u));
}
__device__ __forceinline__ ushort_t f16h(float x) {   // f32 -> f16 (RNE)
    _Float16 h = (_Float16)x;
    return __builtin_bit_cast(ushort_t, h);
}
__device__ __forceinline__ float f16f(ushort_t h) {
    return (float)__builtin_bit_cast(_Float16, h);
}
// quad butterfly adds via DPP (no DS pipe)
__device__ __forceinline__ float quad_add_xor1(float x) {
    return x + __int_as_float(__builtin_amdgcn_mov_dpp(__float_as_int(x), 0xB1, 0xF, 0xF, true));
}
__device__ __forceinline__ float quad_add_xor2(float x) {
    return x + __int_as_float(__builtin_amdgcn_mov_dpp(__float_as_int(x), 0x4E, 0xF, 0xF, true));
}

// Partial-entry bases (chunked split: CK = {2,3,4})
constexpr int EB0 = 0;
constexpr int EB1 = NROW * 2 * WW * 2;         // 18432
constexpr int EB2 = EB1 + NROW * 3 * WW * 2;   // 46080
constexpr int ETOT = EB2 + NROW * 4 * WW * 2;  // 82944

// ---------------------------------------------------------------------------
// D0: weight convert -> SINGLE f16 panel [n][k] (f16x2 GEMM scheme).
// blocks 0..107 -> W_qkv; 108..143 -> W_proj.
// ---------------------------------------------------------------------------
__global__ __launch_bounds__(256)
void convert_w_kernel(const float* __restrict__ Wq, const float* __restrict__ Wp,
                      ushort_t* __restrict__ Bq, ushort_t* __restrict__ Bp)
{
    __shared__ float T[32][36];
    int b = blockIdx.x;
    const float* W; ushort_t* Bb; int N;
    int kt, nt;
    if (b < 108) { W = Wq; Bb = Bq; N = CQKV; kt = b % 6; nt = b / 6; }
    else         { b -= 108; W = Wp; Bb = Bp; N = CIN; kt = b % 6; nt = b / 6; }
    const int k0 = kt * 32, n0 = nt * 32;
    const int tid = threadIdx.x;

    #pragma unroll
    for (int p = 0; p < 4; ++p) {
        int e = p * 256 + tid;
        int r = e >> 5, c = e & 31;
        T[c][r] = W[(long)(k0 + r) * N + n0 + c];
    }
    __syncthreads();
    const int n = tid >> 3;
    const int k4 = (tid & 7) * 4;
    float4 v = *(const float4*)(&T[n][k4]);
    ushort4 hv;
    hv.x = f16h(v.x); hv.y = f16h(v.y); hv.z = f16h(v.z); hv.w = f16h(v.w);
    *(ushort4*)(Bb + (long)(n0 + n) * KW + k0 + k4) = hv;
}

// ---------------------------------------------------------------------------
// D1: f16x2 MFMA GEMM (A = f16 hi + f16 lo, B = single f16 panel). R7-proven.
// ---------------------------------------------------------------------------
__global__ __launch_bounds__(256)
void gemm_mfma_kernel(const float* __restrict__ A, const ushort_t* __restrict__ Bb,
                      const float* __restrict__ bias, ushort_t* __restrict__ Cout, int N)
{
    __shared__ ushort_t As[64][72];
    __shared__ ushort_t Bs[64][72];
    __shared__ float Ct[64][68];

    const int tid = threadIdx.x;
    const int bm = blockIdx.x * 64;
    const int bn = blockIdx.y * 64;

    const int wv = tid >> 6;
    const int lane = tid & 63;
    const int lm = lane & 15;
    const int quad = lane >> 4;
    const int wr = (wv >> 1) * 32;
    const int wc = (wv & 1) * 32;

    const int ar = tid >> 4;
    const int ac4 = (tid & 15) * 4;
    const int br0 = tid >> 3;
    const int bc0 = (tid & 7) * 8;

    f32x4 acc[2][2] = {};

    float4 av[4];
    #pragma unroll
    for (int p = 0; p < 4; ++p)
        av[p] = *(const float4*)(A + (long)(bm + ar + p * 16) * CIN + ac4);
    uint4 nb0 = *(const uint4*)(Bb + (long)(bn + br0) * KW + bc0);
    uint4 nb1 = *(const uint4*)(Bb + (long)(bn + br0 + 32) * KW + bc0);

    #pragma unroll
    for (int g = 0; g < 3; ++g) {
        const uint4 b0 = nb0, b1 = nb1;
        ushort4 hv4[4], lv4[4];
        #pragma unroll
        for (int p = 0; p < 4; ++p) {
            float4 v = av[p];
            hv4[p].x = f16h(v.x); hv4[p].y = f16h(v.y);
            hv4[p].z = f16h(v.z); hv4[p].w = f16h(v.w);
            lv4[p].x = f16h(v.x - f16f(hv4[p].x));
            lv4[p].y = f16h(v.y - f16f(hv4[p].y));
            lv4[p].z = f16h(v.z - f16f(hv4[p].z));
            lv4[p].w = f16h(v.w - f16f(hv4[p].w));
        }
        __syncthreads();                      // prev P1-MFMA done with As/Bs
        #pragma unroll
        for (int p = 0; p < 4; ++p)
            *(ushort4*)(&As[ar + p * 16][ac4]) = hv4[p];
        *(uint4*)(&Bs[br0][bc0])      = b0;
        *(uint4*)(&Bs[br0 + 32][bc0]) = b1;
        if (g < 2) {                          // prefetch next group (B + A)
            const int kk = (g + 1) * 64;
            nb0 = *(const uint4*)(Bb + (long)(bn + br0) * KW + kk + bc0);
            nb1 = *(const uint4*)(Bb + (long)(bn + br0 + 32) * KW + kk + bc0);
            #pragma unroll
            for (int p = 0; p < 4; ++p)
                av[p] = *(const float4*)(A + (long)(bm + ar + p * 16) * CIN + (g + 1) * 64 + ac4);
        }
        __syncthreads();

        #pragma unroll
        for (int ks = 0; ks < 64; ks += 32) {
            half8 af0 = *(const half8*)(&As[wr + lm][ks + quad * 8]);
            half8 af1 = *(const half8*)(&As[wr + 16 + lm][ks + quad * 8]);
            half8 bf0 = *(const half8*)(&Bs[wc + lm][ks + quad * 8]);
            half8 bf1 = *(const half8*)(&Bs[wc + 16 + lm][ks + quad * 8]);
            acc[0][0] = __builtin_amdgcn_mfma_f32_16x16x32_f16(af0, bf0, acc[0][0], 0, 0, 0);
            acc[0][1] = __builtin_amdgcn_mfma_f32_16x16x32_f16(af0, bf1, acc[0][1], 0, 0, 0);
            acc[1][0] = __builtin_amdgcn_mfma_f32_16x16x32_f16(af1, bf0, acc[1][0], 0, 0, 0);
            acc[1][1] = __builtin_amdgcn_mfma_f32_16x16x32_f16(af1, bf1, acc[1][1], 0, 0, 0);
        }
        __syncthreads();                      // P0-MFMA done reading As(hi)
        #pragma unroll
        for (int p = 0; p < 4; ++p)
            *(ushort4*)(&As[ar + p * 16][ac4]) = lv4[p];
        __syncthreads();
        #pragma unroll
        for (int ks = 0; ks < 64; ks += 32) {
            half8 af0 = *(const half8*)(&As[wr + lm][ks + quad * 8]);
            half8 af1 = *(const half8*)(&As[wr + 16 + lm][ks + quad * 8]);
            half8 bf0 = *(const half8*)(&Bs[wc + lm][ks + quad * 8]);
            half8 bf1 = *(const half8*)(&Bs[wc + 16 + lm][ks + quad * 8]);
            acc[0][0] = __builtin_amdgcn_mfma_f32_16x16x32_f16(af0, bf0, acc[0][0], 0, 0, 0);
            acc[0][1] = __builtin_amdgcn_mfma_f32_16x16x32_f16(af0, bf1, acc[0][1], 0, 0, 0);
            acc[1][0] = __builtin_amdgcn_mfma_f32_16x16x32_f16(af1, bf0, acc[1][0], 0, 0, 0);
            acc[1][1] = __builtin_amdgcn_mfma_f32_16x16x32_f16(af1, bf1, acc[1][1], 0, 0, 0);
        }
    }

    // epilogue
    #pragma unroll
    for (int tc = 0; tc < 2; ++tc) {
        const float bv = bias[bn + wc + tc * 16 + lm];
        #pragma unroll
        for (int tr = 0; tr < 2; ++tr) {
            #pragma unroll
            for (int reg = 0; reg < 4; ++reg)
                Ct[wr + tr * 16 + quad * 4 + reg][wc + tc * 16 + lm] = acc[tr][tc][reg] + bv;
        }
    }
    __syncthreads();
    const int orow = tid >> 4;
    const int oc4 = (tid & 15) * 4;
    #pragma unroll
    for (int p = 0; p < 4; ++p) {
        const int r = orow + p * 16;
        float4 v = *(const float4*)(&Ct[r][oc4]);
        ushort4 hv;
        hv.x = bf16h(v.x); hv.y = bf16h(v.y); hv.z = bf16h(v.z); hv.w = bf16h(v.w);
        *(ushort4*)(Cout + (long)(bm + r) * N + bn + oc4) = hv;
    }
}

// ---------------------------------------------------------------------------
// D3: proj GEMM, FUSED COMBINE on the A-path, f16x2 scheme. R7-proven.
// ---------------------------------------------------------------------------
__global__ __launch_bounds__(256)
void gemm_proj_kernel(const float* __restrict__ accs, const float* __restrict__ stats,
                      const ushort_t* __restrict__ Bb, const float* __restrict__ bias,
                      float* __restrict__ Cout)
{
    __shared__ ushort_t As[64][72];
    __shared__ ushort_t Bs[64][72];
    __shared__ float Ct[64][68];

    const int tid = threadIdx.x;
    const int bm = blockIdx.x * 64;
    const int bn = blockIdx.y * 64;

    const int wv = tid >> 6;
    const int lane = tid & 63;
    const int lm = lane & 15;
    const int quad = lane >> 4;
    const int wr = (wv >> 1) * 32;
    const int wc = (wv & 1) * 32;

    const int ar = tid >> 4;
    const int ac4 = (tid & 15) * 4;
    const int a_hd = ac4 >> 5;            // head within scale
    const int a_cc = ac4 & 31;            // channel-4 within head
    const int br0 = tid >> 3;
    const int bc0 = (tid & 7) * 8;

    f32x4 acc[2][2] = {};

    auto load_av = [&](int gg, float4* av) {
        const int CK = gg + 2;
        const int eb = (gg == 0) ? EB0 : (gg == 1 ? EB1 : EB2);
        #pragma unroll
        for (int p = 0; p < 4; ++p) {
            const int q = bm + ar + p * 16;
            const int rr = q / WW;
            const int w = q - rr * WW;
            const int e0 = eb + (rr * CK) * (WW * 2) + w * 2 + a_hd;
            float S = 0.f;
            float4 a = make_float4(0.f, 0.f, 0.f, 0.f);
            #pragma unroll
            for (int c = 0; c < 4; ++c) {
                if (c < CK) {
                    const int e = e0 + c * (WW * 2);
                    S += stats[e];
                    const float4 t = *(const float4*)(accs + (long)e * 32 + a_cc);
                    a.x += t.x; a.y += t.y; a.z += t.z; a.w += t.w;
                }
            }
            const float rs = 1.0f / S;
            av[p] = make_float4(a.x * rs, a.y * rs, a.z * rs, a.w * rs);
        }
    };

    float4 av[4];
    load_av(0, av);
    uint4 nb0 = *(const uint4*)(Bb + (long)(bn + br0) * KW + bc0);
    uint4 nb1 = *(const uint4*)(Bb + (long)(bn + br0 + 32) * KW + bc0);

    #pragma unroll
    for (int g = 0; g < 3; ++g) {
        const uint4 b0 = nb0, b1 = nb1;
        ushort4 hv4[4], lv4[4];
        #pragma unroll
        for (int p = 0; p < 4; ++p) {
            float4 v = av[p];
            hv4[p].x = f16h(v.x); hv4[p].y = f16h(v.y);
            hv4[p].z = f16h(v.z); hv4[p].w = f16h(v.w);
            lv4[p].x = f16h(v.x - f16f(hv4[p].x));
            lv4[p].y = f16h(v.y - f16f(hv4[p].y));
            lv4[p].z = f16h(v.z - f16f(hv4[p].z));
            lv4[p].w = f16h(v.w - f16f(hv4[p].w));
        }
        __syncthreads();
        #pragma unroll
        for (int p = 0; p < 4; ++p)
            *(ushort4*)(&As[ar + p * 16][ac4]) = hv4[p];
        *(uint4*)(&Bs[br0][bc0])      = b0;
        *(uint4*)(&Bs[br0 + 32][bc0]) = b1;
        if (g < 2) {
            const int kk = (g + 1) * 64;
            nb0 = *(const uint4*)(Bb + (long)(bn + br0) * KW + kk + bc0);
            nb1 = *(const uint4*)(Bb + (long)(bn + br0 + 32) * KW + kk + bc0);
            load_av(g + 1, av);
        }
        __syncthreads();

        #pragma unroll
        for (int ks = 0; ks < 64; ks += 32) {
            half8 af0 = *(const half8*)(&As[wr + lm][ks + quad * 8]);
            half8 af1 = *(const half8*)(&As[wr + 16 + lm][ks + quad * 8]);
            half8 bf0 = *(const half8*)(&Bs[wc + lm][ks + quad * 8]);
            half8 bf1 = *(const half8*)(&Bs[wc + 16 + lm][ks + quad * 8]);
            acc[0][0] = __builtin_amdgcn_mfma_f32_16x16x32_f16(af0, bf0, acc[0][0], 0, 0, 0);
            acc[0][1] = __builtin_amdgcn_mfma_f32_16x16x32_f16(af0, bf1, acc[0][1], 0, 0, 0);
            acc[1][0] = __builtin_amdgcn_mfma_f32_16x16x32_f16(af1, bf0, acc[1][0], 0, 0, 0);
            acc[1][1] = __builtin_amdgcn_mfma_f32_16x16x32_f16(af1, bf1, acc[1][1], 0, 0, 0);
        }
        __syncthreads();
        #pragma unroll
        for (int p = 0; p < 4; ++p)
            *(ushort4*)(&As[ar + p * 16][ac4]) = lv4[p];
        __syncthreads();
        #pragma unroll
        for (int ks = 0; ks < 64; ks += 32) {
            half8 af0 = *(const half8*)(&As[wr + lm][ks + quad * 8]);
            half8 af1 = *(const half8*)(&As[wr + 16 + lm][ks + quad * 8]);
            half8 bf0 = *(const half8*)(&Bs[wc + lm][ks + quad * 8]);
            half8 bf1 = *(const half8*)(&Bs[wc + 16 + lm][ks + quad * 8]);
            acc[0][0] = __builtin_amdgcn_mfma_f32_16x16x32_f16(af0, bf0, acc[0][0], 0, 0, 0);
            acc[0][1] = __builtin_amdgcn_mfma_f32_16x16x32_f16(af0, bf1, acc[0][1], 0, 0, 0);
            acc[1][0] = __builtin_amdgcn_mfma_f32_16x16x32_f16(af1, bf0, acc[1][0], 0, 0, 0);
            acc[1][1] = __builtin_amdgcn_mfma_f32_16x16x32_f16(af1, bf1, acc[1][1], 0, 0, 0);
        }
    }

    #pragma unroll
    for (int tc = 0; tc < 2; ++tc) {
        const float bv = bias[bn + wc + tc * 16 + lm];
        #pragma unroll
        for (int tr = 0; tr < 2; ++tr) {
            #pragma unroll
            for (int reg = 0; reg < 4; ++reg)
                Ct[wr + tr * 16 + quad * 4 + reg][wc + tc * 16 + lm] = acc[tr][tc][reg] + bv;
        }
    }
    __syncthreads();
    const int orow = tid >> 4;
    const int oc4 = (tid & 15) * 4;
    #pragma unroll
    for (int p = 0; p < 4; ++p) {
        const int r = orow + p * 16;
        float4 v = *(const float4*)(&Ct[r][oc4]);
        *(float4*)(Cout + (long)(bm + r) * CIN + bn + oc4) = v;
    }
}

// ---------------------------------------------------------------------------
// D2: attention split — 2 QUERIES PER THREAD (band-overlap DS reduction).
// Queries w and w+1 share K-1 of K neighbor rows; one thread owns both and
// reads the <=K+1-row union window ONCE per tile -> DS bytes 0.57x (the
// modeled D2 bottleneck). Per-query arithmetic is op-and-order identical to
// the proven kernel -> bit-identical output. Block = 192 thr = 2 r-rows x
// (12 w-slots x 2 hd x 4 d8); LDS = 2 r-tiles x triple buffer = 41.5 KB
// (3 blocks/CU). Out-of-window rows masked via ?:0 (quad-uniform masks);
// row read clamped to 23 to stay in-bounds on the masked tail iteration.
// ---------------------------------------------------------------------------
constexpr int KROW = 72;              // ushort stride per w (64 ch + 8 pad)
constexpr int RT = 24 * KROW;         // one r-tile = 1728 ushorts

template<int K>
__device__ __forceinline__
void split_chunk(const ushort_t* __restrict__ qkv,
                 float* __restrict__ accs, float* __restrict__ stats,
                 int r0, int c, int nchunks, int scale, int ebase,
                 int tid, ushort_t* __restrict__ ksh, ushort_t* __restrict__ vsh)
{
    const int rhalf = tid >= 96 ? 1 : 0;
    const int t96 = tid - rhalf * 96;
    const int slot = t96 >> 3;          // 0..11
    const int hd = (t96 >> 2) & 1;
    const int d8 = t96 & 3;
    const int w0 = slot * 2, w1 = w0 + 1;
    const int r = r0 + rhalf;

    const int i0 = 2 * c;
    const int ni = (K - i0) < 2 ? (K - i0) : 2;
    const int NT = ni * K;              // >= 2 always

    const int dq = r / HH, hq = r % HH;
    int sd = dq - K / 2; sd = sd < 0 ? 0 : (sd > DD - K ? DD - K : sd);
    int sh = hq - K / 2; sh = sh < 0 ? 0 : (sh > HH - K ? HH - K : sh);
    int sw0 = w0 - K / 2; sw0 = sw0 < 0 ? 0 : (sw0 > WW - K ? WW - K : sw0);
    int sw1 = w1 - K / 2; sw1 = sw1 < 0 ? 0 : (sw1 > WW - K ? WW - K : sw1);

    // q fragments for both queries, pre-scaled by scale*log2e
    const long qbase = (long)((dq * HH + hq) * WW) * CQKV + scale * 192 + hd * 32 + d8 * 8;
    uint4 qu0 = *(const uint4*)(qkv + qbase + (long)w0 * CQKV);
    uint4 qu1 = *(const uint4*)(qkv + qbase + (long)w1 * CQKV);
    float2 qf0[4] = {unpack2(qu0.x), unpack2(qu0.y), unpack2(qu0.z), unpack2(qu0.w)};
    float2 qf1[4] = {unpack2(qu1.x), unpack2(qu1.y), unpack2(qu1.z), unpack2(qu1.w)};
    #pragma unroll
    for (int t = 0; t < 4; ++t) {
        qf0[t].x *= SCALE_LOG2E; qf0[t].y *= SCALE_LOG2E;
        qf1[t].x *= SCALE_LOG2E; qf1[t].y *= SCALE_LOG2E;
    }

    // staging: 96 threads per r-half cover 24 rows x 4 ch16-groups
    const int sr = t96 >> 2;            // 0..23
    const int sc = (t96 & 3) * 16;      // 0,16,32,48

    auto src_ptr = [&](int t) {
        int i = i0 + t / K;
        int j = t - (t / K) * K;
        return qkv + (long)(((sd + i) * HH + (sh + j)) * WW + sr) * CQKV
             + scale * 192 + sc;
    };
    auto lds_off = [&](int buf) {
        return (buf * 2 + rhalf) * RT + sr * KROW + sc;
    };

    // prologue: issue t=0 and t=1; commit t=0 into buf0
    uint4 ck0, ck1, cv0, cv1;
    {
        const ushort_t* p0 = src_ptr(0);
        uint4 k0a = *(const uint4*)(p0 + 64);
        uint4 k0b = *(const uint4*)(p0 + 72);
        uint4 v0a = *(const uint4*)(p0 + 128);
        uint4 v0b = *(const uint4*)(p0 + 136);
        const ushort_t* p1 = src_ptr(1);   // NT >= 2 always
        ck0 = *(const uint4*)(p1 + 64);
        ck1 = *(const uint4*)(p1 + 72);
        cv0 = *(const uint4*)(p1 + 128);
        cv1 = *(const uint4*)(p1 + 136);
        const int lb = lds_off(0);
        *(uint4*)(ksh + lb)     = k0a;
        *(uint4*)(ksh + lb + 8) = k0b;
        *(uint4*)(vsh + lb)     = v0a;
        *(uint4*)(vsh + lb + 8) = v0b;
    }

    float sum0 = 0.f, sum1 = 0.f;
    float2 a0[4] = {}, a1[4] = {};
    const int choff = hd * 32 + d8 * 8;

    for (int t = 0; t < NT; ++t) {
        __syncthreads();
        // issue loads for t+2 (consumed at bottom of t+1)
        uint4 nk0, nk1, nv0, nv1;
        const bool issue = (t + 2 < NT);
        if (issue) {
            const ushort_t* pn = src_ptr(t + 2);
            nk0 = *(const uint4*)(pn + 64);
            nk1 = *(const uint4*)(pn + 72);
            nv0 = *(const uint4*)(pn + 128);
            nv1 = *(const uint4*)(pn + 136);
        }

        const int bb = ((t % 3) * 2 + rhalf) * RT + choff;
        #pragma unroll
        for (int n = 0; n <= K; ++n) {       // union window, <=K+1 rows
            const int row = sw0 + n;
            const int rowc = row < WW ? row : WW - 1;   // masked-tail clamp
            const bool m0 = (n < K);                         // w0: [sw0,sw0+K)
            const bool m1 = (row >= sw1) && (row < sw1 + K); // w1 window
            uint4 ku = *(const uint4*)(ksh + bb + rowc * KROW);
            float2 k0 = unpack2(ku.x), k1 = unpack2(ku.y),
                   k2 = unpack2(ku.z), k3 = unpack2(ku.w);
            float2 d0, d1;
            d0.x  = qf0[0].x * k0.x; d0.y  = qf0[0].y * k0.y;
            d0.x += qf0[1].x * k1.x; d0.y += qf0[1].y * k1.y;
            d0.x += qf0[2].x * k2.x; d0.y += qf0[2].y * k2.y;
            d0.x += qf0[3].x * k3.x; d0.y += qf0[3].y * k3.y;
            d1.x  = qf1[0].x * k0.x; d1.y  = qf1[0].y * k0.y;
            d1.x += qf1[1].x * k1.x; d1.y += qf1[1].y * k1.y;
            d1.x += qf1[2].x * k2.x; d1.y += qf1[2].y * k2.y;
            d1.x += qf1[3].x * k3.x; d1.y += qf1[3].y * k3.y;
            float p0 = d0.x + d0.y;
            p0 = quad_add_xor1(p0);
            p0 = quad_add_xor2(p0);
            float p1 = d1.x + d1.y;
            p1 = quad_add_xor1(p1);
            p1 = quad_add_xor2(p1);
            float pr0 = m0 ? exp2f(p0) : 0.f;
            float pr1 = m1 ? exp2f(p1) : 0.f;
            sum0 += pr0;
            sum1 += pr1;
            uint4 vu = *(const uint4*)(vsh + bb + rowc * KROW);
            float2 v0 = unpack2(vu.x), v1 = unpack2(vu.y),
                   v2 = unpack2(vu.z), v3 = unpack2(vu.w);
            a0[0].x += pr0 * v0.x; a0[0].y += pr0 * v0.y;
            a0[1].x += pr0 * v1.x; a0[1].y += pr0 * v1.y;
            a0[2].x += pr0 * v2.x; a0[2].y += pr0 * v2.y;
            a0[3].x += pr0 * v3.x; a0[3].y += pr0 * v3.y;
            a1[0].x += pr1 * v0.x; a1[0].y += pr1 * v0.y;
            a1[1].x += pr1 * v1.x; a1[1].y += pr1 * v1.y;
            a1[2].x += pr1 * v2.x; a1[2].y += pr1 * v2.y;
            a1[3].x += pr1 * v3.x; a1[3].y += pr1 * v3.y;
        }

        // commit t+1 into buf (t+1)%3 (loads issued one iteration ago)
        if (t + 1 < NT) {
            const int lb = lds_off((t + 1) % 3);
            *(uint4*)(ksh + lb)     = ck0;
            *(uint4*)(ksh + lb + 8) = ck1;
            *(uint4*)(vsh + lb)     = cv0;
            *(uint4*)(vsh + lb + 8) = cv1;
        }
        ck0 = nk0; ck1 = nk1; cv0 = nv0; cv1 = nv1;
    }

    const int e0 = ebase + ((r * nchunks + c) * WW + w0) * 2 + hd;
    const int e1 = e0 + 2;                         // w1 = w0+1
    if (d8 == 0) {
        stats[e0] = sum0;
        stats[e1] = sum1;
    }
    float* ap0 = accs + (long)e0 * 32 + d8 * 8;
    *(float4*)(ap0)     = make_float4(a0[0].x, a0[0].y, a0[1].x, a0[1].y);
    *(float4*)(ap0 + 4) = make_float4(a0[2].x, a0[2].y, a0[3].x, a0[3].y);
    float* ap1 = accs + (long)e1 * 32 + d8 * 8;
    *(float4*)(ap1)     = make_float4(a1[0].x, a1[0].y, a1[1].x, a1[1].y);
    *(float4*)(ap1 + 4) = make_float4(a1[2].x, a1[2].y, a1[3].x, a1[3].y);
}

__global__ __launch_bounds__(192)
void na3d_split_kernel(const ushort_t* __restrict__ qkv,
                       float* __restrict__ accs, float* __restrict__ stats)
{
    __shared__ alignas(16) ushort_t ksh[3 * 2 * RT];   // 20736 B
    __shared__ alignas(16) ushort_t vsh[3 * 2 * RT];   // 20736 B

    const int tid = threadIdx.x;

    // Per-class XCD-chunked swizzle (regions 384/288/192, all %8 == 0).
    const int orig = blockIdx.x;
    int bid;
    if (orig < 384) {
        bid = (orig & 7) * 48 + (orig >> 3);
    } else if (orig < 672) {
        const int t = orig - 384;
        bid = 384 + (t & 7) * 36 + (t >> 3);
    } else {
        const int t = orig - 672;
        bid = 672 + (t & 7) * 24 + (t >> 3);
    }

    if (bid < 384) {                       // K=7: 96 r-pairs x 4 chunks
        int rp = bid >> 2, c = bid & 3;
        split_chunk<7>(qkv, accs, stats, rp * 2, c, 4, 2, EB2, tid, ksh, vsh);
    } else if (bid < 672) {                // K=5: 96 r-pairs x 3 chunks
        int t = bid - 384;
        int rp = t / 3, c = t - (t / 3) * 3;
        split_chunk<5>(qkv, accs, stats, rp * 2, c, 3, 1, EB1, tid, ksh, vsh);
    } else {                               // K=3: 96 r-pairs x 2 chunks
        int t = bid - 672;
        int rp = t >> 1, c = t & 1;
        split_chunk<3>(qkv, accs, stats, rp * 2, c, 2, 0, EB0, tid, ksh, vsh);
    }
}

// ---------------------------------------------------------------------------
extern "C" void kernel_launch(void* const* d_in, const int* in_sizes, int n_in,
                              void* d_out, int out_size, void* d_ws, size_t ws_size,
                              hipStream_t stream)
{
    const float* x      = (const float*)d_in[0];
    const float* W_qkv  = (const float*)d_in[1];
    const float* b_qkv  = (const float*)d_in[2];
    const float* W_proj = (const float*)d_in[3];
    const float* b_proj = (const float*)d_in[4];
    float* out = (float*)d_out;

    // workspace (~16.5 MB; >= 22.5 MB proven available)
    float* accs    = (float*)d_ws;                         // ETOT*32 fl
    float* stats   = accs + (long)ETOT * 32;               // ETOT fl
    ushort_t* qkvb = (ushort_t*)(stats + ETOT);            // NQ*576 us (bf16)
    ushort_t* Wbq  = qkvb + (long)NQ * CQKV;               // 576*192 us (f16)
    ushort_t* Wbp  = Wbq + (long)CQKV * KW;                // 192*192 us (f16)

    // D0: weight conversion (one dispatch, both weights, single f16 panel)
    convert_w_kernel<<<dim3(144), 256, 0, stream>>>(W_qkv, W_proj, Wbq, Wbp);

    // D1: qkv = x @ W_qkv + b_qkv -> bf16 (f16x2 MFMA scheme)
    gemm_mfma_kernel<<<dim3(NQ / 64, CQKV / 64), 256, 0, stream>>>(x, Wbq, b_qkv, qkvb, CQKV);

    // D2: attention split -> partials (2 queries/thread, union-window reads)
    na3d_split_kernel<<<dim3(384 + 288 + 192), 192, 0, stream>>>(qkvb, accs, stats);

    // D3: out = combine(accs,stats) @ W_proj + b_proj -> fp32 (combine fused)
    gemm_proj_kernel<<<dim3(NQ / 64, CIN / 64), 256, 0, stream>>>(accs, stats, Wbp, b_proj, out);
}